// Round 17
// baseline (180.551 us; speedup 1.0000x reference)
//
#include <hip/hip_runtime.h>
#include <hip/hip_bf16.h>

// ParallelNCA on MFMA: 64 grouped MLPs (144->128->16) over 3x3 perception.
// Round 17 = r15/16 pipeline with the per-tile serial chain cut:
//  - residual loads prefetched one tile ahead (L2 latency hidden under compute)
//  - out-store deferred across the tail barrier (store-ack off critical path)
//  - loop-invariant bias loads hoisted out of the tile loop.
// Dataflow/tiling/traffic identical to r16 (FETCH 157MB verified).

typedef __attribute__((ext_vector_type(8))) short short8;   // 8 bf16 frag
typedef __attribute__((ext_vector_type(4))) float f32x4;    // MFMA acc

constexpr int Bn  = 16;
constexpr int Mn  = 64;
constexpr int Cn  = 16;
constexpr int Hd  = 128;
constexpr int K9  = 144;
constexpr int MCn = 1024;
constexpr int NP  = 64;           // pixels per tile (2 image rows)
constexpr int CHUNKS = 18;        // 144 ch = 18 x 8ch(16B) chunks
constexpr int BUFB = CHUNKS * NP * 16;  // 18432 B per Pt buffer
constexpr int HT_STRIDE = 272;    // bytes/pixel row of Ht (17 16B slots, odd)
constexpr int NT  = 256;
constexpr int TILES = 4;          // tiles per block (quarter image)

// pixel-major padded bf16 x: [b][h' 0..33][w' 0..33][mc 0..1023]
constexpr size_t XPM_SLABS = 34 * 34;
constexpr size_t XPM_B     = XPM_SLABS * MCn;               // ushorts per b
constexpr size_t XPM_BYTES = (size_t)Bn * XPM_B * 2;        // 37,879,808
constexpr size_t W1_ELEMS  = (size_t)Mn * Hd * K9;
constexpr size_t W2_ELEMS  = (size_t)Mn * Cn * Hd;
constexpr size_t WS_NEED   = XPM_BYTES + 2 * (W1_ELEMS + W2_ELEMS);

constexpr int NB_BORDER = Bn * 132;
constexpr int NB_W      = (int)((W1_ELEMS + W2_ELEMS) / 4 / 256);

__device__ __forceinline__ ushort f2bf(float f) {
    return __bfloat16_as_ushort(__float2bfloat16(f));
}
__device__ __forceinline__ float bf2f(ushort u) {
    union { uint i; float f; } v; v.i = (uint)u << 16; return v.f;
}

// ---------------------------------------------------------------------------
// prep: x [b][mc][32][32] f32 -> xpm [b][h+1][w+1][mc] bf16 (interior only)
// ---------------------------------------------------------------------------
__global__ __launch_bounds__(256)
void prep_xpm(const float* __restrict__ x, ushort* __restrict__ xpm)
{
    const int bid = blockIdx.x;
    const int b  = bid >> 7;
    const int h  = (bid >> 2) & 31;
    const int ck = bid & 3;
    const int tid = threadIdx.x;

    __shared__ ushort T[256][36];

    const int mc = ck * 256 + tid;
    const float* src = x + (((size_t)b * MCn + mc) * 32 + h) * 32;
    #pragma unroll
    for (int j = 0; j < 8; ++j) {
        const float4 f = *(const float4*)(src + 4 * j);
        uint2 pk;
        pk.x = (uint)f2bf(f.x) | ((uint)f2bf(f.y) << 16);
        pk.y = (uint)f2bf(f.z) | ((uint)f2bf(f.w) << 16);
        *(uint2*)&T[tid][4 * j] = pk;
    }
    __syncthreads();

    ushort* const dstb = xpm + (size_t)b * XPM_B + ((size_t)(h + 1) * 34) * MCn
                       + ck * 256;
    #pragma unroll
    for (int rep = 0; rep < 4; ++rep) {
        const int q8 = tid & 31;
        const int w  = (tid >> 5) + 8 * rep;
        ushort tmp[8];
        #pragma unroll
        for (int k2 = 0; k2 < 8; ++k2) tmp[k2] = T[8 * q8 + k2][w];
        uint4 v;
        v.x = (uint)tmp[0] | ((uint)tmp[1] << 16);
        v.y = (uint)tmp[2] | ((uint)tmp[3] << 16);
        v.z = (uint)tmp[4] | ((uint)tmp[5] << 16);
        v.w = (uint)tmp[6] | ((uint)tmp[7] << 16);
        *(uint4*)(dstb + (size_t)(w + 1) * MCn + 8 * q8) = v;
    }
}

// aux: border zero-fill + weight cvt
__global__ __launch_bounds__(256)
void prep_aux(const float* __restrict__ w1, const float* __restrict__ w2,
              ushort* __restrict__ w1bf, ushort* __restrict__ w2bf,
              ushort* __restrict__ xpm)
{
    const int bid = blockIdx.x;
    const int tid = threadIdx.x;
    if (bid < NB_BORDER) {
        const int b   = bid / 132;
        const int pos = bid % 132;
        int hh, ww;
        if      (pos < 34)  { hh = 0;              ww = pos;        }
        else if (pos < 68)  { hh = 33;             ww = pos - 34;   }
        else if (pos < 100) { hh = pos - 68 + 1;   ww = 0;          }
        else                { hh = pos - 100 + 1;  ww = 33;         }
        ushort* dst = xpm + (size_t)b * XPM_B + ((size_t)hh * 34 + ww) * MCn
                    + tid * 4;
        *(uint2*)dst = (uint2){0, 0};
    } else {
        const size_t i = ((size_t)(bid - NB_BORDER) * 256 + tid) * 4;
        const float* src; ushort* dst; size_t e;
        if (i < W1_ELEMS) { src = w1; dst = w1bf; e = i; }
        else              { src = w2; dst = w2bf; e = i - W1_ELEMS; }
        const float4 f = *(const float4*)(src + e);
        uint2 pk;
        pk.x = (uint)f2bf(f.x) | ((uint)f2bf(f.y) << 16);
        pk.y = (uint)f2bf(f.z) | ((uint)f2bf(f.w) << 16);
        *(uint2*)(dst + e) = pk;
    }
}

// ---------------------------------------------------------------------------
// main kernel: block = (m, batch, quarter); 4 tiles of 64 px, double-buffered
// Pt, async gather via global_load_lds. Pt layout: [chunk 0..17][pixel][16B].
// ---------------------------------------------------------------------------
__global__ __launch_bounds__(NT, 4)
void nca_pipe(const ushort* __restrict__ xpm,
              const ushort* __restrict__ w1bf, const float* __restrict__ b1,
              const ushort* __restrict__ w2bf, const float* __restrict__ b2,
              float* __restrict__ out)
{
    __shared__ __align__(16) char U[2 * BUFB];   // 36864 B

    const int tid  = threadIdx.x;
    const int lane = tid & 63;
    const int wid  = tid >> 6;      // wave 0..3
    const int lr   = lane & 15;
    const int lk   = lane >> 4;

    // decode: bid = j*8 + xcd; j = q*128 + mch*64 + bhi*32 + mlo
    const int bid = blockIdx.x;
    const int xcd = bid & 7;
    const int j   = bid >> 3;            // 0..511
    const int mlo = j & 31;
    const int bhi = (j >> 5) & 1;
    const int mch = (j >> 6) & 1;
    const int q   = j >> 7;              // 0..3
    const int m   = mch * 32 + mlo;
    const int bb  = bhi * 8 + xcd;       // batch 0..15 (pinned to one XCD)

    const ushort* const xpb = xpm + (size_t)bb * XPM_B;

    // ---------- weights (held in regs for 4 tiles) ----------
    short8 a1[2][5];
    #pragma unroll
    for (int rt = 0; rt < 2; ++rt) {
        const int row = wid * 32 + rt * 16 + lr;
        const ushort* wr = w1bf + (m * Hd + row) * K9;
        #pragma unroll
        for (int ks = 0; ks < 5; ++ks) {
            const int k0 = ks * 32 + lk * 8;
            a1[rt][ks] = (k0 < K9) ? *(const short8*)(wr + k0)
                                   : (short8){0,0,0,0,0,0,0,0};
        }
    }
    short8 a2[4];
    #pragma unroll
    for (int ks = 0; ks < 4; ++ks)
        a2[ks] = *(const short8*)(w2bf + (m * Cn + lr) * Hd + ks * 32 + lk * 8);

    // ---------- loop-invariant biases ----------
    const float4 bsA = *(const float4*)(b1 + m * Hd + wid * 32 + lk * 4);        // rt=0
    const float4 bsB = *(const float4*)(b1 + m * Hd + wid * 32 + 16 + lk * 4);   // rt=1
    const float bsv  = b2[m * Cn + lr];

    // ---------- per-chunk gather tables (wave wid owns chunks wid+4i) ----------
    const unsigned long long TAB = 0xA62918405ull;   // (dr+1)|((dc+1)<<2)
    int cb[5];
    #pragma unroll
    for (int i = 0; i < 5; ++i) {
        const int c = wid + 4 * i;
        const int cc = (c < CHUNKS) ? c : 0;
        const int ch = m * K9 + cc * 8;
        const int s  = ch >> 10;
        const int mc = ch & 1023;
        const uint nib = (uint)(TAB >> (4 * s)) & 15u;
        const int dr = (int)(nib & 3u) - 1;
        const int dc = (int)(nib >> 2) - 1;
        cb[i] = ((dr + 1) * 34 + (dc + 1)) * 1024 + mc;
    }
    const int laneoff = ((lane >> 5) * 34 + (lane & 31)) * 1024;   // ushorts

    auto STAGE = [&](int t, char* buf) {
        const ushort* srcb = xpb + (size_t)(q * 8 + t * 2) * 34816 + laneoff;
        #pragma unroll
        for (int i = 0; i < 5; ++i) {
            const int c = wid + 4 * i;
            if (c < CHUNKS) {
                __builtin_amdgcn_global_load_lds(
                    (const __attribute__((address_space(1))) void*)(srcb + cb[i]),
                    (__attribute__((address_space(3))) void*)(buf + c * 1024),
                    16, 0, 0);
            }
        }
    };

    // residual prefetch: lane -> channel c=lr, 4 px starting at gp0
    ushort rcur[4], rnxt[4];
    auto RES = [&](int t, ushort* r) {
        const int gp0 = q * 256 + t * NP + wid * 16 + lk * 4;
        const int h = gp0 >> 5, w0 = gp0 & 31;
        const ushort* rp = xpb + ((h + 1) * 34 + (w0 + 1)) * MCn + m * Cn + lr;
        r[0] = rp[0]; r[1] = rp[MCn]; r[2] = rp[2 * MCn]; r[3] = rp[3 * MCn];
    };

    // prologue: tile 0 staged + residual(0)
    STAGE(0, U);
    RES(0, rcur);
    asm volatile("s_waitcnt vmcnt(0)" ::: "memory");
    __syncthreads();

    f32x4 o_prev;
    size_t idx_prev = 0;
    #pragma unroll 1
    for (int t = 0; t < TILES; ++t) {
        char* const A = U + (t & 1) * BUFB;
        char* const B = U + ((t + 1) & 1) * BUFB;

        // deferred store of previous tile's output (off critical path)
        if (t > 0) *(f32x4*)(out + idx_prev) = o_prev;

        if (t + 1 < TILES) {
            STAGE(t + 1, B);       // async, lands during compute
            RES(t + 1, rnxt);      // residual prefetch, consumed next iter
        }

        // ---------- GEMM1: hdn = w1 @ P, 128x64x144 ----------
        f32x4 acc[2][4];
        #pragma unroll
        for (int i = 0; i < 2; ++i)
            #pragma unroll
            for (int jj = 0; jj < 4; ++jj) acc[i][jj] = (f32x4){0.f, 0.f, 0.f, 0.f};

        #pragma unroll
        for (int ct = 0; ct < 4; ++ct) {
            const char* pb = A + (ct * 16 + lr) * 16;
            short8 bfrag[5];
            #pragma unroll
            for (int ks = 0; ks < 4; ++ks)
                bfrag[ks] = *(const short8*)(pb + (ks * 4 + lk) * 1024);
            bfrag[4] = (short8){0,0,0,0,0,0,0,0};
            if (lk < 2)                            // chunks 16,17 = ch 128..144
                bfrag[4] = *(const short8*)(pb + (16 + lk) * 1024);
            #pragma unroll
            for (int ks = 0; ks < 5; ++ks) {
                acc[0][ct] = __builtin_amdgcn_mfma_f32_16x16x32_bf16(a1[0][ks], bfrag[ks], acc[0][ct], 0, 0, 0);
                acc[1][ct] = __builtin_amdgcn_mfma_f32_16x16x32_bf16(a1[1][ks], bfrag[ks], acc[1][ct], 0, 0, 0);
            }
        }
        __syncthreads();   // A(Pt) reads done -> reuse A as Ht

        // ---------- bias+relu -> Ht[p][hd] bf16 (into A) ----------
        #pragma unroll
        for (int rt = 0; rt < 2; ++rt) {
            const int hd0 = wid * 32 + rt * 16 + lk * 4;   // C/D row=(lane>>4)*4+reg
            const float4 bs = rt ? bsB : bsA;
            #pragma unroll
            for (int ct = 0; ct < 4; ++ct) {
                const int p = ct * 16 + lr;                // C/D col = lane&15
                const f32x4 v = acc[rt][ct];
                uint2 pk;
                pk.x = (uint)f2bf(fmaxf(v[0] + bs.x, 0.f)) |
                       ((uint)f2bf(fmaxf(v[1] + bs.y, 0.f)) << 16);
                pk.y = (uint)f2bf(fmaxf(v[2] + bs.z, 0.f)) |
                       ((uint)f2bf(fmaxf(v[3] + bs.w, 0.f)) << 16);
                *(uint2*)(A + p * HT_STRIDE + hd0 * 2) = pk;
            }
        }
        __syncthreads();

        // ---------- GEMM2 (operand-swapped): D[px][c] = Ht · w2^T ----------
        f32x4 acc2;
        {
            const char* base = A + (wid * 16 + lr) * HT_STRIDE + lk * 16;
            short8 hf[4];
            #pragma unroll
            for (int ks = 0; ks < 4; ++ks)
                hf[ks] = *(const short8*)(base + ks * 64);
            f32x4 a = (f32x4){0.f, 0.f, 0.f, 0.f};
            #pragma unroll
            for (int ks = 0; ks < 4; ++ks)
                a = __builtin_amdgcn_mfma_f32_16x16x32_bf16(hf[ks], a2[ks], a, 0, 0, 0);
            acc2 = a;
        }

        // ---------- epilogue into registers (store deferred) ----------
        {
            const int gp0 = q * 256 + t * NP + wid * 16 + lk * 4;
            o_prev[0] = acc2[0] + bsv + bf2f(rcur[0]);
            o_prev[1] = acc2[1] + bsv + bf2f(rcur[1]);
            o_prev[2] = acc2[2] + bsv + bf2f(rcur[2]);
            o_prev[3] = acc2[3] + bsv + bf2f(rcur[3]);
            idx_prev  = ((size_t)(bb * MCn + m * Cn + lr)) * 1024 + gp0;
            rcur[0] = rnxt[0]; rcur[1] = rnxt[1];
            rcur[2] = rnxt[2]; rcur[3] = rnxt[3];
        }

        // next tile's Pt landed + all Ht reads done before STAGE overwrites A
        asm volatile("s_waitcnt vmcnt(0)" ::: "memory");
        __syncthreads();
    }
    *(f32x4*)(out + idx_prev) = o_prev;   // final tile's store
}

// ---------------------------------------------------------------------------
// fallback (f32-direct, round 6): used when ws_size < WS_NEED
// ---------------------------------------------------------------------------
constexpr int PT_STRIDE_FB = 304;
__global__ __launch_bounds__(NT, 4)
void nca_mfma_f32src(const float* __restrict__ x,  const float* __restrict__ w1,
                     const float* __restrict__ b1, const float* __restrict__ w2,
                     const float* __restrict__ b2, float* __restrict__ out)
{
    __shared__ __align__(16) char U[128 * PT_STRIDE_FB + 16];
    char* const PtL = U;
    char* const HtL = U;

    const int tid  = threadIdx.x;
    const int lane = tid & 63;
    const int wid  = tid >> 6;
    const int lr   = lane & 15;
    const int lk   = lane >> 4;

    const int bid = blockIdx.x;
    const int xcd = bid & 7;
    const int jb  = bid >> 3;
    const int m   = jb & 63;
    const int g   = (jb >> 6) * 8 + xcd;
    const int b   = g >> 3;
    const int p0  = (g & 7) * 128;

    if (tid <= 128) {
        char* z = PtL + tid * PT_STRIDE_FB + (tid < 128 ? 288 : 0);
        *(int4*)z = (int4){0, 0, 0, 0};
    }

    short8 a1[2][5];
    #pragma unroll
    for (int rt = 0; rt < 2; ++rt) {
        const int row = wid * 32 + rt * 16 + lr;
        const float* wr = w1 + (m * Hd + row) * K9;
        #pragma unroll
        for (int ks = 0; ks < 5; ++ks) {
            const int k0 = ks * 32 + lk * 8;
            short8 t;
            if (k0 < K9) {
                const float4 f0 = *(const float4*)(wr + k0);
                const float4 f1 = *(const float4*)(wr + k0 + 4);
                t[0] = (short)f2bf(f0.x); t[1] = (short)f2bf(f0.y);
                t[2] = (short)f2bf(f0.z); t[3] = (short)f2bf(f0.w);
                t[4] = (short)f2bf(f1.x); t[5] = (short)f2bf(f1.y);
                t[6] = (short)f2bf(f1.z); t[7] = (short)f2bf(f1.w);
            } else t = (short8){0,0,0,0,0,0,0,0};
            a1[rt][ks] = t;
        }
    }
    short8 a2[4];
    #pragma unroll
    for (int ks = 0; ks < 4; ++ks) {
        const float* wr = w2 + (m * Cn + lr) * Hd + ks * 32 + lk * 8;
        const float4 f0 = *(const float4*)(wr);
        const float4 f1 = *(const float4*)(wr + 4);
        short8 t;
        t[0] = (short)f2bf(f0.x); t[1] = (short)f2bf(f0.y);
        t[2] = (short)f2bf(f0.z); t[3] = (short)f2bf(f0.w);
        t[4] = (short)f2bf(f1.x); t[5] = (short)f2bf(f1.y);
        t[6] = (short)f2bf(f1.z); t[7] = (short)f2bf(f1.w);
        a2[ks] = t;
    }
    {
        const int s     = tid & 7;
        const int kpl   = (tid >> 3) & 7;
        const int r     = tid >> 6;
        const int rbase = (g & 7) * 4 + r;
        const float* xb = x + (size_t)b * (MCn * 1024);
        const unsigned long long TAB = 0xA62918405ull;
        #pragma unroll
        for (int it = 0; it < 9; ++it) {
            const int kp = it * 8 + kpl;
            float4 hv[2];
            #pragma unroll
            for (int half = 0; half < 2; ++half) {
                const int ch = m * K9 + kp * 2 + half;
                const int sh = ch >> 10;
                const int mc = ch & 1023;
                const uint nib = (uint)(TAB >> (4 * sh)) & 15u;
                const int dr = (int)(nib & 3u) - 1;
                const int dc = (int)(nib >> 2) - 1;
                const int row = rbase + dr;
                const int wb  = 4 * s + dc;
                const int wc  = min(max(wb, 0), 28);
                float4 f = {0.f, 0.f, 0.f, 0.f};
                if ((unsigned)row < 32u)
                    f = *(const float4*)(xb + (mc * 32 + row) * 32 + wc);
                if (wb < 0)       { f.w = f.z; f.z = f.y; f.y = f.x; f.x = 0.f; }
                else if (wb > 28) { f.x = f.y; f.y = f.z; f.z = f.w; f.w = 0.f; }
                hv[half] = f;
            }
            char* dst = PtL + (r * 32 + 4 * s) * PT_STRIDE_FB + kp * 4;
            *(uint*)(dst)                    = (uint)f2bf(hv[0].x) | ((uint)f2bf(hv[1].x) << 16);
            *(uint*)(dst + PT_STRIDE_FB)     = (uint)f2bf(hv[0].y) | ((uint)f2bf(hv[1].y) << 16);
            *(uint*)(dst + 2 * PT_STRIDE_FB) = (uint)f2bf(hv[0].z) | ((uint)f2bf(hv[1].z) << 16);
            *(uint*)(dst + 3 * PT_STRIDE_FB) = (uint)f2bf(hv[0].w) | ((uint)f2bf(hv[1].w) << 16);
        }
    }
    __syncthreads();

    f32x4 acc[2][8];
    #pragma unroll
    for (int i = 0; i < 2; ++i)
        #pragma unroll
        for (int jj = 0; jj < 8; ++jj) acc[i][jj] = (f32x4){0.f, 0.f, 0.f, 0.f};
    #pragma unroll
    for (int ct = 0; ct < 8; ++ct) {
        const int p = ct * 16 + lr;
        const char* base = PtL + p * PT_STRIDE_FB + lk * 16;
        short8 bfrag[5];
        #pragma unroll
        for (int ks = 0; ks < 5; ++ks)
            bfrag[ks] = *(const short8*)(base + ks * 64);
        #pragma unroll
        for (int ks = 0; ks < 5; ++ks) {
            acc[0][ct] = __builtin_amdgcn_mfma_f32_16x16x32_bf16(a1[0][ks], bfrag[ks], acc[0][ct], 0, 0, 0);
            acc[1][ct] = __builtin_amdgcn_mfma_f32_16x16x32_bf16(a1[1][ks], bfrag[ks], acc[1][ct], 0, 0, 0);
        }
    }
    __syncthreads();
    #pragma unroll
    for (int rt = 0; rt < 2; ++rt) {
        const int hd0 = wid * 32 + rt * 16 + lk * 4;
        const float4 bs = *(const float4*)(b1 + m * Hd + hd0);
        #pragma unroll
        for (int ct = 0; ct < 8; ++ct) {
            const int p = ct * 16 + lr;
            const f32x4 v = acc[rt][ct];
            uint2 pk;
            pk.x = (uint)f2bf(fmaxf(v[0] + bs.x, 0.f)) |
                   ((uint)f2bf(fmaxf(v[1] + bs.y, 0.f)) << 16);
            pk.y = (uint)f2bf(fmaxf(v[2] + bs.z, 0.f)) |
                   ((uint)f2bf(fmaxf(v[3] + bs.w, 0.f)) << 16);
            *(uint2*)(HtL + p * HT_STRIDE + hd0 * 2) = pk;
        }
    }
    __syncthreads();
    f32x4 acc2[2];
    #pragma unroll
    for (int jj = 0; jj < 2; ++jj) {
        const int ct = wid * 2 + jj;
        const int p  = ct * 16 + lr;
        const char* base = HtL + p * HT_STRIDE + lk * 16;
        short8 bbf[4];
        #pragma unroll
        for (int ks = 0; ks < 4; ++ks)
            bbf[ks] = *(const short8*)(base + ks * 64);
        f32x4 a = (f32x4){0.f, 0.f, 0.f, 0.f};
        #pragma unroll
        for (int ks = 0; ks < 4; ++ks)
            a = __builtin_amdgcn_mfma_f32_16x16x32_bf16(a2[ks], bbf[ks], a, 0, 0, 0);
        acc2[jj] = a;
    }
    const float4 b2v = *(const float4*)(b2 + m * Cn + lk * 4);
    const float bsv[4] = {b2v.x, b2v.y, b2v.z, b2v.w};
    #pragma unroll
    for (int jj = 0; jj < 2; ++jj) {
        const int ct = wid * 2 + jj;
        const int gp = p0 + ct * 16 + lr;
        #pragma unroll
        for (int r = 0; r < 4; ++r) {
            const int c   = lk * 4 + r;
            const size_t idx = ((size_t)(b * MCn + m * Cn + c)) * 1024 + gp;
            out[idx] = x[idx] + acc2[jj][r] + bsv[r];
        }
    }
}

extern "C" void kernel_launch(void* const* d_in, const int* in_sizes, int n_in,
                              void* d_out, int out_size, void* d_ws, size_t ws_size,
                              hipStream_t stream)
{
    const float* x  = (const float*)d_in[0];
    const float* w1 = (const float*)d_in[1];
    const float* b1 = (const float*)d_in[2];
    const float* w2 = (const float*)d_in[3];
    const float* b2 = (const float*)d_in[4];
    float* out = (float*)d_out;

    if (ws_size >= WS_NEED) {
        ushort* xpm  = (ushort*)d_ws;
        ushort* w1bf = (ushort*)((char*)d_ws + XPM_BYTES);
        ushort* w2bf = w1bf + W1_ELEMS;
        prep_xpm<<<Bn * 32 * 4, 256, 0, stream>>>(x, xpm);
        prep_aux<<<NB_BORDER + NB_W, 256, 0, stream>>>(w1, w2, w1bf, w2bf, xpm);
        nca_pipe<<<Mn * Bn * TILES, NT, 0, stream>>>(xpm, w1bf, b1, w2bf, b2, out);  // 4096
    } else {
        nca_mfma_f32src<<<Mn * (Bn * 1024 / 128), NT, 0, stream>>>(x, w1, b1, w2, b2, out);
    }
}